// Round 10
// baseline (296.044 us; speedup 1.0000x reference)
//
#include <hip/hip_runtime.h>
#include <hip/hip_bf16.h>

#define BB 4
#define NN 400
#define DD 100
#define SS 512

typedef __attribute__((ext_vector_type(8))) short bf16x8;
typedef __attribute__((ext_vector_type(4))) float f32x4;

__device__ __forceinline__ float prelu_f(float v, float a) { return v >= 0.f ? v : a * v; }

__device__ __forceinline__ unsigned short f2bf(float x) {
    union { __hip_bfloat16 h; unsigned short u; } c;
    c.h = __float2bfloat16(x);   // RNE
    return c.u;
}
__device__ __forceinline__ float bf2f(unsigned short u) {
    return __uint_as_float(((unsigned)u) << 16);
}

__device__ __forceinline__ bf16x8 ldfrag(const unsigned short* rowp, int grp) {
    ushort4 lo = *(const ushort4*)(rowp + grp * 4);
    ushort4 hi = *(const ushort4*)(rowp + grp * 4 + 16);
    bf16x8 r = {(short)lo.x, (short)lo.y, (short)lo.z, (short)lo.w,
                (short)hi.x, (short)hi.y, (short)hi.z, (short)hi.w};
    return r;
}

#define LPAD 136   // row stride (ushorts): 68 dwords == 4 mod 32 -> <=2-way on frag reads

// =====================================================================
// MFMA bf16 GEMM, 256 thr (4 waves 2x2), tile 64x64, K-step 128.
// flags: bit0 = A is bf16 (lda/sA in ushort elems); bit1 = B is bf16
// (transB=1 only).  A2p/B2p: optional second fp32 pointer summed at
// staging (folds a split-K reduce into this GEMM's load).
// nsplit>1: raw partials to C[(b*nsplit+split)*M*N].
// nsplit==1 epilogues: 0 none | 4 prelu(v+bias[n],*alpha)+res | 5 pdist
// (triangular: blocks i0>n0 return; mirror writes fill lower half).
// =====================================================================
__global__ __launch_bounds__(256)
void mmfa(const void* __restrict__ Ap, const void* __restrict__ A2p, int lda, int sA,
          const void* __restrict__ Bp, const void* __restrict__ B2p, int ldb, int sB,
          int transB, int flags,
          float* __restrict__ C, int sC, int M, int N, int K,
          int nsplit, int kchunk, int EP,
          const float* __restrict__ bias, const float* __restrict__ alpha,
          const float* __restrict__ rv, int rvStride,
          const float* __restrict__ res, int sRes)
{
    int zz = blockIdx.z;
    int b = zz / nsplit, split = zz - b * nsplit;
    int kbeg = split * kchunk, kend = min(K, kbeg + kchunk);
    int i0 = blockIdx.x * 64, n0 = blockIdx.y * 64;
    if (EP == 5 && i0 > n0) return;          // symmetric: lower mirrored

    int tid = threadIdx.x;
    int lane = tid & 63, wave = tid >> 6;
    int r16 = lane & 15, grp = (lane >> 4) & 3;
    int wr = wave >> 1, wc = wave & 1;       // 2x2 wave grid

    __shared__ unsigned short sa[64][LPAD];
    __shared__ unsigned short sb[64][LPAD];

    f32x4 acc[2][2];
#pragma unroll
    for (int fm = 0; fm < 2; ++fm)
#pragma unroll
        for (int fn = 0; fn < 2; ++fn)
            acc[fm][fn] = (f32x4){0.f, 0.f, 0.f, 0.f};

    for (int kt = kbeg; kt < kend; kt += 128) {
        // ---- stage A (64 rows x 128 k)
        if (flags & 1) {
            const unsigned short* Ab = (const unsigned short*)Ap + (size_t)b * sA;
#pragma unroll
            for (int it = 0; it < 8; ++it) {
                int idx = tid + it * 256;
                int row = idx >> 5, kq = (idx & 31) * 4;
                ushort4 u = {0, 0, 0, 0};
                if (i0 + row < M && kt + kq + 4 <= kend)
                    u = *(const ushort4*)&Ab[(size_t)(i0 + row) * lda + kt + kq];
                *(ushort4*)&sa[row][kq] = u;
            }
        } else {
            const float* Ab  = (const float*)Ap + (size_t)b * sA;
            const float* Ab2 = A2p ? (const float*)A2p + (size_t)b * sA : nullptr;
#pragma unroll
            for (int it = 0; it < 8; ++it) {
                int idx = tid + it * 256;
                int row = idx >> 5, kq = (idx & 31) * 4;
                float4 v = make_float4(0.f, 0.f, 0.f, 0.f);
                if (i0 + row < M && kt + kq + 4 <= kend) {
                    v = *(const float4*)&Ab[(size_t)(i0 + row) * lda + kt + kq];
                    if (Ab2) {
                        float4 w = *(const float4*)&Ab2[(size_t)(i0 + row) * lda + kt + kq];
                        v.x += w.x; v.y += w.y; v.z += w.z; v.w += w.w;
                    }
                }
                ushort4 u;
                u.x = f2bf(v.x); u.y = f2bf(v.y); u.z = f2bf(v.z); u.w = f2bf(v.w);
                *(ushort4*)&sa[row][kq] = u;
            }
        }
        // ---- stage B
        if (transB) {
            if (flags & 2) {
                const unsigned short* Bb = (const unsigned short*)Bp + (size_t)b * sB;
#pragma unroll
                for (int it = 0; it < 8; ++it) {
                    int idx = tid + it * 256;
                    int row = idx >> 5, kq = (idx & 31) * 4;
                    ushort4 u = {0, 0, 0, 0};
                    if (n0 + row < N && kt + kq + 4 <= kend)
                        u = *(const ushort4*)&Bb[(size_t)(n0 + row) * ldb + kt + kq];
                    *(ushort4*)&sb[row][kq] = u;
                }
            } else {
                const float* Bb  = (const float*)Bp + (size_t)b * sB;
                const float* Bb2 = B2p ? (const float*)B2p + (size_t)b * sB : nullptr;
#pragma unroll
                for (int it = 0; it < 8; ++it) {
                    int idx = tid + it * 256;
                    int row = idx >> 5, kq = (idx & 31) * 4;
                    float4 v = make_float4(0.f, 0.f, 0.f, 0.f);
                    if (n0 + row < N && kt + kq + 4 <= kend) {
                        v = *(const float4*)&Bb[(size_t)(n0 + row) * ldb + kt + kq];
                        if (Bb2) {
                            float4 w = *(const float4*)&Bb2[(size_t)(n0 + row) * ldb + kt + kq];
                            v.x += w.x; v.y += w.y; v.z += w.z; v.w += w.w;
                        }
                    }
                    ushort4 u;
                    u.x = f2bf(v.x); u.y = f2bf(v.y); u.z = f2bf(v.z); u.w = f2bf(v.w);
                    *(ushort4*)&sb[row][kq] = u;
                }
            }
        } else {
            const float* Bb  = (const float*)Bp + (size_t)b * sB;
            const float* Bb2 = B2p ? (const float*)B2p + (size_t)b * sB : nullptr;
#pragma unroll
            for (int it = 0; it < 8; ++it) {
                int idx = tid + it * 256;
                int kk = idx >> 4;           // 0..127
                int nq = (idx & 15) * 4;     // 0..60
                float4 v = make_float4(0.f, 0.f, 0.f, 0.f);
                if (kt + kk < kend && n0 + nq + 4 <= N) {
                    v = *(const float4*)&Bb[(size_t)(kt + kk) * ldb + n0 + nq];
                    if (Bb2) {
                        float4 w = *(const float4*)&Bb2[(size_t)(kt + kk) * ldb + n0 + nq];
                        v.x += w.x; v.y += w.y; v.z += w.z; v.w += w.w;
                    }
                }
                sb[nq + 0][kk] = f2bf(v.x);
                sb[nq + 1][kk] = f2bf(v.y);
                sb[nq + 2][kk] = f2bf(v.z);
                sb[nq + 3][kk] = f2bf(v.w);
            }
        }
        __syncthreads();

#pragma unroll
        for (int ks = 0; ks < 4; ++ks) {     // 4 x K=32 sub-windows
            bf16x8 a0 = ldfrag(&sa[wr * 32 + r16][ks * 32], grp);
            bf16x8 a1 = ldfrag(&sa[wr * 32 + 16 + r16][ks * 32], grp);
            bf16x8 b0 = ldfrag(&sb[wc * 32 + r16][ks * 32], grp);
            bf16x8 b1 = ldfrag(&sb[wc * 32 + 16 + r16][ks * 32], grp);
            acc[0][0] = __builtin_amdgcn_mfma_f32_16x16x32_bf16(a0, b0, acc[0][0], 0, 0, 0);
            acc[0][1] = __builtin_amdgcn_mfma_f32_16x16x32_bf16(a0, b1, acc[0][1], 0, 0, 0);
            acc[1][0] = __builtin_amdgcn_mfma_f32_16x16x32_bf16(a1, b0, acc[1][0], 0, 0, 0);
            acc[1][1] = __builtin_amdgcn_mfma_f32_16x16x32_bf16(a1, b1, acc[1][1], 0, 0, 0);
        }
        __syncthreads();
    }

    // ---- store: i = i0 + wr*32 + fm*16 + grp*4 + reg, n = n0 + wc*32 + fn*16 + r16
    if (nsplit > 1) {
        float* Pp = C + (size_t)(b * nsplit + split) * M * N;
#pragma unroll
        for (int fm = 0; fm < 2; ++fm)
#pragma unroll
            for (int fn = 0; fn < 2; ++fn)
#pragma unroll
                for (int reg = 0; reg < 4; ++reg) {
                    int i = i0 + wr * 32 + fm * 16 + grp * 4 + reg;
                    int n = n0 + wc * 32 + fn * 16 + r16;
                    if (i < M && n < N) Pp[(size_t)i * N + n] = acc[fm][fn][reg];
                }
        return;
    }

    float al = alpha ? *alpha : 0.f;
    const float* rvb = rv ? rv + (size_t)b * rvStride : nullptr;
    float* Cb = C + (size_t)b * sC;
#pragma unroll
    for (int fm = 0; fm < 2; ++fm)
#pragma unroll
        for (int fn = 0; fn < 2; ++fn)
#pragma unroll
            for (int reg = 0; reg < 4; ++reg) {
                int i = i0 + wr * 32 + fm * 16 + grp * 4 + reg;
                int n = n0 + wc * 32 + fn * 16 + r16;
                if (i >= M || n >= N) continue;
                float v = acc[fm][fn][reg];
                if (EP == 4) {
                    v = prelu_f(v + bias[n], al) + res[(size_t)b * sRes + (size_t)i * N + n];
                } else if (EP == 5) {
                    float d2 = rvb[i] + rvb[n] - 2.f * v;
                    v = (i == n) ? 1.f : sqrtf(fmaxf(d2, 0.f));
                }
                Cb[(size_t)i * N + n] = v;
                if (EP == 5) Cb[(size_t)n * N + i] = v;   // mirror (same value; diag benign)
            }
}

// =====================================================================
// kscore: fused scores + row-softmax + sq.  Block = 64-row panel of one
// batch, all 512 cols.  scores = G1_panel @ Ax^T, Ax = axp0 + axp1
// (split-K partials summed at staging).  Writes P as bf16 + sq.
// K = 100 (padded to 128 with zeros).
// =====================================================================
__global__ __launch_bounds__(256)
void kscore(const float* __restrict__ G1, const float* __restrict__ axp,
            unsigned short* __restrict__ Pb, float* __restrict__ sq)
{
    int b = blockIdx.z;
    int i0 = blockIdx.x * 64;
    int tid = threadIdx.x;
    int lane = tid & 63, wave = tid >> 6;
    int r16 = lane & 15, grp = (lane >> 4) & 3;
    int wr = wave >> 1, wc = wave & 1;

    __shared__ unsigned short sa[64][LPAD];
    __shared__ unsigned short sb[64][LPAD];
    __shared__ float rowred[2][64];

    const float* p0 = axp + (size_t)(b * 2 + 0) * (SS * DD);
    const float* p1 = axp + (size_t)(b * 2 + 1) * (SS * DD);

    // stage A = G1 rows [i0, i0+64), k zero-padded 100->128
#pragma unroll
    for (int it = 0; it < 8; ++it) {
        int idx = tid + it * 256;
        int row = idx >> 5, kq = (idx & 31) * 4;
        float4 v = make_float4(0.f, 0.f, 0.f, 0.f);
        if (kq + 4 <= DD) v = *(const float4*)&G1[(size_t)(i0 + row) * DD + kq];
        ushort4 u;
        u.x = f2bf(v.x); u.y = f2bf(v.y); u.z = f2bf(v.z); u.w = f2bf(v.w);
        *(ushort4*)&sa[row][kq] = u;
    }

    f32x4 acc[8][2][2];
#pragma unroll
    for (int nt = 0; nt < 8; ++nt)
#pragma unroll
        for (int fm = 0; fm < 2; ++fm)
#pragma unroll
            for (int fn = 0; fn < 2; ++fn)
                acc[nt][fm][fn] = (f32x4){0.f, 0.f, 0.f, 0.f};

#pragma unroll
    for (int nt = 0; nt < 8; ++nt) {
        int n0 = nt * 64;
        __syncthreads();                     // sb reuse guard (covers sa on nt=0)
#pragma unroll
        for (int it = 0; it < 8; ++it) {
            int idx = tid + it * 256;
            int row = idx >> 5, kq = (idx & 31) * 4;
            float4 v = make_float4(0.f, 0.f, 0.f, 0.f);
            if (kq + 4 <= DD) {
                float4 a = *(const float4*)&p0[(size_t)(n0 + row) * DD + kq];
                float4 c = *(const float4*)&p1[(size_t)(n0 + row) * DD + kq];
                v.x = a.x + c.x; v.y = a.y + c.y; v.z = a.z + c.z; v.w = a.w + c.w;
            }
            ushort4 u;
            u.x = f2bf(v.x); u.y = f2bf(v.y); u.z = f2bf(v.z); u.w = f2bf(v.w);
            *(ushort4*)&sb[row][kq] = u;
        }
        __syncthreads();
#pragma unroll
        for (int ks = 0; ks < 4; ++ks) {
            bf16x8 a0 = ldfrag(&sa[wr * 32 + r16][ks * 32], grp);
            bf16x8 a1 = ldfrag(&sa[wr * 32 + 16 + r16][ks * 32], grp);
            bf16x8 b0 = ldfrag(&sb[wc * 32 + r16][ks * 32], grp);
            bf16x8 b1 = ldfrag(&sb[wc * 32 + 16 + r16][ks * 32], grp);
            acc[nt][0][0] = __builtin_amdgcn_mfma_f32_16x16x32_bf16(a0, b0, acc[nt][0][0], 0, 0, 0);
            acc[nt][0][1] = __builtin_amdgcn_mfma_f32_16x16x32_bf16(a0, b1, acc[nt][0][1], 0, 0, 0);
            acc[nt][1][0] = __builtin_amdgcn_mfma_f32_16x16x32_bf16(a1, b0, acc[nt][1][0], 0, 0, 0);
            acc[nt][1][1] = __builtin_amdgcn_mfma_f32_16x16x32_bf16(a1, b1, acc[nt][1][1], 0, 0, 0);
        }
    }

    // ---- softmax over the 512 cols of each of this thread's 8 row-positions.
    // row_local = wr*32 + fm*16 + grp*4 + reg; this thread's cols: nt(8) x fn(2).
    float mx[8];
#pragma unroll
    for (int fm = 0; fm < 2; ++fm)
#pragma unroll
        for (int reg = 0; reg < 4; ++reg) {
            int p = fm * 4 + reg;
            float m = -INFINITY;
#pragma unroll
            for (int nt = 0; nt < 8; ++nt)
#pragma unroll
                for (int fn = 0; fn < 2; ++fn)
                    m = fmaxf(m, acc[nt][fm][fn][reg]);
            mx[p] = m;
        }
#pragma unroll
    for (int off = 1; off < 16; off <<= 1)
#pragma unroll
        for (int p = 0; p < 8; ++p)
            mx[p] = fmaxf(mx[p], __shfl_xor(mx[p], off, 64));
    __syncthreads();
    if (r16 == 0) {
#pragma unroll
        for (int fm = 0; fm < 2; ++fm)
#pragma unroll
            for (int reg = 0; reg < 4; ++reg)
                rowred[wc][wr * 32 + fm * 16 + grp * 4 + reg] = mx[fm * 4 + reg];
    }
    __syncthreads();
#pragma unroll
    for (int fm = 0; fm < 2; ++fm)
#pragma unroll
        for (int reg = 0; reg < 4; ++reg) {
            int rl = wr * 32 + fm * 16 + grp * 4 + reg;
            mx[fm * 4 + reg] = fmaxf(rowred[0][rl], rowred[1][rl]);
        }

    float sm[8];
#pragma unroll
    for (int fm = 0; fm < 2; ++fm)
#pragma unroll
        for (int reg = 0; reg < 4; ++reg) {
            int p = fm * 4 + reg;
            float s = 0.f;
#pragma unroll
            for (int nt = 0; nt < 8; ++nt)
#pragma unroll
                for (int fn = 0; fn < 2; ++fn)
                    s += expf(acc[nt][fm][fn][reg] - mx[p]);
            sm[p] = s;
        }
#pragma unroll
    for (int off = 1; off < 16; off <<= 1)
#pragma unroll
        for (int p = 0; p < 8; ++p)
            sm[p] += __shfl_xor(sm[p], off, 64);
    __syncthreads();
    if (r16 == 0) {
#pragma unroll
        for (int fm = 0; fm < 2; ++fm)
#pragma unroll
            for (int reg = 0; reg < 4; ++reg)
                rowred[wc][wr * 32 + fm * 16 + grp * 4 + reg] = sm[fm * 4 + reg];
    }
    __syncthreads();
#pragma unroll
    for (int fm = 0; fm < 2; ++fm)
#pragma unroll
        for (int reg = 0; reg < 4; ++reg) {
            int rl = wr * 32 + fm * 16 + grp * 4 + reg;
            sm[fm * 4 + reg] = 1.f / (rowred[0][rl] + rowred[1][rl]);
        }

    // ---- write P (bf16) and accumulate sq = sum(bf16(p)^2)
    float qs[8];
#pragma unroll
    for (int fm = 0; fm < 2; ++fm)
#pragma unroll
        for (int reg = 0; reg < 4; ++reg) {
            int p = fm * 4 + reg;
            int rowg = i0 + wr * 32 + fm * 16 + grp * 4 + reg;
            unsigned short* Prow = Pb + (size_t)(b * SS + rowg) * SS;
            float q = 0.f;
#pragma unroll
            for (int nt = 0; nt < 8; ++nt)
#pragma unroll
                for (int fn = 0; fn < 2; ++fn) {
                    float e = expf(acc[nt][fm][fn][reg] - mx[p]) * sm[p];
                    unsigned short ub = f2bf(e);
                    Prow[nt * 64 + wc * 32 + fn * 16 + r16] = ub;
                    float pf = bf2f(ub);
                    q += pf * pf;
                }
            qs[p] = q;
        }
#pragma unroll
    for (int off = 1; off < 16; off <<= 1)
#pragma unroll
        for (int p = 0; p < 8; ++p)
            qs[p] += __shfl_xor(qs[p], off, 64);
    __syncthreads();
    if (r16 == 0) {
#pragma unroll
        for (int fm = 0; fm < 2; ++fm)
#pragma unroll
            for (int reg = 0; reg < 4; ++reg)
                rowred[wc][wr * 32 + fm * 16 + grp * 4 + reg] = qs[fm * 4 + reg];
    }
    __syncthreads();
    if (wc == 0 && r16 == 0) {
#pragma unroll
        for (int fm = 0; fm < 2; ++fm)
#pragma unroll
            for (int reg = 0; reg < 4; ++reg) {
                int rl = wr * 32 + fm * 16 + grp * 4 + reg;
                sq[b * SS + i0 + rl] = rowred[0][rl] + rowred[1][rl];
            }
    }
}

// =====================================================================
// Split-K reduce with epilogue.  One float4 per thread.
// EP: 0 none | 1 prelu(v+bias[n],*alpha) | 2 v*rv[i] | 3 relu(rv[i]*v+bias[n])
// =====================================================================
__global__ __launch_bounds__(256)
void k_reduce(const float* __restrict__ part, int nsplit, float* __restrict__ C, int sC,
              int M, int N, int EP, const float* __restrict__ bias,
              const float* __restrict__ alpha, const float* __restrict__ rv, int rvStride)
{
    int b = blockIdx.y;
    int MN = M * N;
    int flat = (blockIdx.x * 256 + threadIdx.x) * 4;
    if (flat >= MN) return;
    const float* p = part + (size_t)b * nsplit * MN + flat;
    float4 v = *(const float4*)p;
    for (int s = 1; s < nsplit; ++s) {
        float4 w = *(const float4*)(p + (size_t)s * MN);
        v.x += w.x; v.y += w.y; v.z += w.z; v.w += w.w;
    }
    float o[4] = {v.x, v.y, v.z, v.w};
    int i = flat / N, n = flat - i * N;     // N % 4 == 0: float4 never crosses a row
    if (EP == 1) {
        float al = *alpha;
#pragma unroll
        for (int j = 0; j < 4; ++j) o[j] = prelu_f(o[j] + bias[n + j], al);
    } else if (EP == 2) {
        float r = rv[(size_t)b * rvStride + i];
#pragma unroll
        for (int j = 0; j < 4; ++j) o[j] *= r;
    } else if (EP == 3) {
        float r = rv[(size_t)b * rvStride + i];
#pragma unroll
        for (int j = 0; j < 4; ++j) { float t = r * o[j] + bias[n + j]; o[j] = t > 0.f ? t : 0.f; }
    }
    float* co = C + (size_t)b * sC + flat;
    *(float4*)co = make_float4(o[0], o[1], o[2], o[3]);
}

// =====================================================================
// dh[row] = rsqrt(rowsum(Bm))
// =====================================================================
__global__ __launch_bounds__(512)
void k_dh(const float* __restrict__ Bm, float* __restrict__ dh)
{
    int row = blockIdx.x;
    int t = threadIdx.x;
    int w = t >> 6, lane = t & 63;
    __shared__ float sm[8];
    float v = Bm[(size_t)row * SS + t];
    for (int off = 32; off; off >>= 1) v += __shfl_xor(v, off, 64);
    if (lane == 0) sm[w] = v;
    __syncthreads();
    if (t == 0) {
        float r = 0.f;
#pragma unroll
        for (int i = 0; i < 8; ++i) r += sm[i];
        dh[row] = rsqrtf(r);
    }
}

// =====================================================================
// Logits + softmax over n.  block = (b, 8 s-rows), 256 thr.
// div written in (b, n, s) layout.
// =====================================================================
__global__ __launch_bounds__(256)
void k_div8(const float* __restrict__ h1, const float* __restrict__ h2,
            const float* __restrict__ b4a, const float* __restrict__ a4ap,
            const float* __restrict__ W4b, const float* __restrict__ b4bp,
            const float* __restrict__ a4bp, float* __restrict__ divT)
{
    int b = blockIdx.y;
    int s0 = blockIdx.x * 8;
    int tid = threadIdx.x;

    __shared__ float sh[8][104];
    __shared__ float sw[100];
    __shared__ float L[8][400];

    for (int idx = tid; idx < 800; idx += 256) {
        int s = idx / 100, d = idx - 100 * s;
        sh[s][d] = h2[((size_t)(b * SS + s0 + s)) * DD + d] + b4a[d];
    }
    if (tid < 100) sw[tid] = W4b[tid];
    __syncthreads();

    float a4a = *a4ap, a4b = *a4bp, b4b = *b4bp;

    for (int n = tid; n < NN; n += 256) {
        const float* h1r = &h1[((size_t)b * NN + n) * DD];
        float accs[8] = {0.f, 0.f, 0.f, 0.f, 0.f, 0.f, 0.f, 0.f};
        for (int j = 0; j < DD; j += 4) {
            float4 hv = *(const float4*)&h1r[j];
            float4 wv = *(const float4*)&sw[j];
#pragma unroll
            for (int s = 0; s < 8; ++s) {
                float4 cv = *(const float4*)&sh[s][j];
                float x0 = hv.x + cv.x; x0 = x0 > 0.f ? x0 : a4a * x0;
                float x1 = hv.y + cv.y; x1 = x1 > 0.f ? x1 : a4a * x1;
                float x2 = hv.z + cv.z; x2 = x2 > 0.f ? x2 : a4a * x2;
                float x3 = hv.w + cv.w; x3 = x3 > 0.f ? x3 : a4a * x3;
                accs[s] += x0 * wv.x + x1 * wv.y + x2 * wv.z + x3 * wv.w;
            }
        }
#pragma unroll
        for (int s = 0; s < 8; ++s) L[s][n] = prelu_f(accs[s] + b4b, a4b);
    }
    __syncthreads();

    int w = tid >> 6, lane = tid & 63;
    for (int si = w; si < 8; si += 4) {
        float m = -INFINITY;
        for (int n = lane; n < NN; n += 64) m = fmaxf(m, L[si][n]);
        for (int off = 32; off; off >>= 1) m = fmaxf(m, __shfl_xor(m, off, 64));
        float ss = 0.f;
        for (int n = lane; n < NN; n += 64) {
            float e = expf(L[si][n] - m);
            L[si][n] = e;
            ss += e;
        }
        for (int off = 32; off; off >>= 1) ss += __shfl_xor(ss, off, 64);
        float inv = 1.f / ss;
        for (int n = lane; n < NN; n += 64)
            divT[((size_t)b * NN + n) * SS + s0 + si] = L[si][n] * inv;
    }
}

extern "C" void kernel_launch(void* const* d_in, const int* in_sizes, int n_in,
                              void* d_out, int out_size, void* d_ws, size_t ws_size,
                              hipStream_t stream) {
    const float* x   = (const float*)d_in[0];
    const float* G   = (const float*)d_in[1];
    const float* Am  = (const float*)d_in[2];
    const float* Wgf = (const float*)d_in[3];
    const float* bgf = (const float*)d_in[4];
    const float* agf = (const float*)d_in[5];
    const float* Wg  = (const float*)d_in[6];
    const float* bg  = (const float*)d_in[7];
    const float* W4a = (const float*)d_in[8];
    const float* b4a = (const float*)d_in[9];
    const float* a4a = (const float*)d_in[10];
    const float* W4b = (const float*)d_in[11];
    const float* b4b = (const float*)d_in[12];
    const float* a4b = (const float*)d_in[13];
    const float* W5  = (const float*)d_in[14];
    const float* b5  = (const float*)d_in[15];
    const float* a5  = (const float*)d_in[16];
    float* out = (float*)d_out;

    float* ws = (float*)d_ws;
    float* G1     = ws + 0;                        // 51200
    float* partAx = ws + 51200;                    // 409600 (also reused for T1s/gx partials)
    float* Bm     = ws + 460800;                   // 1048576
    float* sq     = ws + 1509376;                  // 2048
    float* dh     = ws + 1511424;                  // 2048
    float* partW  = ws + 1513472;                  // 409600
    float* T1s    = ws + 1923072;                  // 204800
    float* gx     = ws + 2127872;                  // 204800
    float* h1     = ws + 2332672;                  // 160000
    float* h2     = ws + 2492672;                  // 204800
    float* divT   = ws + 2697472;                  // 819200
    float* partB  = ws + 3516672;                  // 320000
    unsigned short* Pb = (unsigned short*)(ws + 3836672);  // 1048576 ushorts
    float* partG  = ws + 4360960;                  // 102400

    // 1. G1 = prelu(G @ Wgf^T + bgf)   split-K 2 + reduce           [2 dispatches]
    mmfa<<<dim3(8, 2, 2), 256, 0, stream>>>(G, nullptr, NN, 0, Wgf, nullptr, NN, 0, 1, 0,
        partG, 0, SS, DD, NN, 2, 200, 0, nullptr, nullptr, nullptr, 0, nullptr, 0);
    k_reduce<<<dim3(50, 1), 256, 0, stream>>>(partG, 2, G1, SS * DD, SS, DD, 1, bgf, agf, nullptr, 0);
    // 2. Ax partials (reduce folded into kscore staging)             [1]
    mmfa<<<dim3(8, 2, 2 * BB), 256, 0, stream>>>(Am, nullptr, NN, 0, x, nullptr, DD, NN * DD, 0, 0,
        partAx, 0, SS, DD, NN, 2, 200, 0, nullptr, nullptr, nullptr, 0, nullptr, 0);
    // 3. kscore: scores + softmax + sq, P stored bf16                [1]
    kscore<<<dim3(8, 1, BB), 256, 0, stream>>>(G1, partAx, Pb, sq);
    // 4. Bm = pdist(P @ P^T), bf16 operands, triangular + mirror     [1]
    mmfa<<<dim3(8, 8, BB), 256, 0, stream>>>(Pb, nullptr, SS, SS * SS, Pb, nullptr, SS, SS * SS, 1, 3,
        Bm, SS * SS, SS, SS, SS, 1, SS, 5, nullptr, nullptr, sq, SS, nullptr, 0);
    // 5. dh                                                           [1]
    k_dh<<<BB * SS, 512, 0, stream>>>(Bm, dh);
    // 6. PW partials = P @ Wg^T (A bf16; reduce folded into step 7)  [1]
    mmfa<<<dim3(8, 2, 2 * BB), 256, 0, stream>>>(Pb, nullptr, SS, SS * SS, Wg, nullptr, SS, 0, 1, 1,
        partW, 0, SS, DD, SS, 2, 256, 0, nullptr, nullptr, nullptr, 0, nullptr, 0);
    // 7. T1s = diag(dh) @ (Bm @ (PW0+PW1))   split-K 2 + reduce EP=2 [2]
    mmfa<<<dim3(8, 2, 2 * BB), 256, 0, stream>>>(Bm, nullptr, SS, SS * SS,
        partW, partW + SS * DD, DD, 2 * SS * DD, 0, 0,
        partAx, 0, SS, DD, SS, 2, 256, 0, nullptr, nullptr, nullptr, 0, nullptr, 0);
    k_reduce<<<dim3(50, BB), 256, 0, stream>>>(partAx, 2, T1s, SS * DD, SS, DD, 2, nullptr, nullptr, dh, SS);
    // 8. gx = relu(diag(dh) @ (Bm @ T1s) + bg) split-K 2 + reduce    [2]
    mmfa<<<dim3(8, 2, 2 * BB), 256, 0, stream>>>(Bm, nullptr, SS, SS * SS,
        T1s, nullptr, DD, SS * DD, 0, 0,
        partAx, 0, SS, DD, SS, 2, 256, 0, nullptr, nullptr, nullptr, 0, nullptr, 0);
    k_reduce<<<dim3(50, BB), 256, 0, stream>>>(partAx, 2, gx, SS * DD, SS, DD, 3, bg, nullptr, dh, SS);
    // 9. h1 = x @ W4a[:, :100]^T                                      [1]
    mmfa<<<dim3(7, 2, BB), 256, 0, stream>>>(x, nullptr, DD, NN * DD, W4a, nullptr, 2 * DD, 0, 1, 0,
        h1, NN * DD, NN, DD, DD, 1, DD, 0, nullptr, nullptr, nullptr, 0, nullptr, 0);
    // 10. h2 = gx @ W4a[:, 100:]^T                                    [1]
    mmfa<<<dim3(8, 2, BB), 256, 0, stream>>>(gx, nullptr, DD, SS * DD, W4a + DD, nullptr, 2 * DD, 0, 1, 0,
        h2, SS * DD, SS, DD, DD, 1, DD, 0, nullptr, nullptr, nullptr, 0, nullptr, 0);
    // 11. div (b,n,s) = softmax_n(logits)                             [1]
    k_div8<<<dim3(SS / 8, BB), 256, 0, stream>>>(h1, h2, b4a, a4a, W4b, b4b, a4b, divT);
    // 12. tmp partials = div @ gx (reduce folded into step 13)        [1]
    mmfa<<<dim3(7, 2, 2 * BB), 256, 0, stream>>>(divT, nullptr, SS, NN * SS, gx, nullptr, DD, SS * DD, 0, 0,
        partB, 0, NN, DD, SS, 2, 256, 0, nullptr, nullptr, nullptr, 0, nullptr, 0);
    // 13. out = prelu((tmp0+tmp1) @ W5^T + b5, a5) + x                [1]
    mmfa<<<dim3(7, 2, BB), 256, 0, stream>>>(partB, partB + NN * DD, DD, 2 * NN * DD,
        W5, nullptr, DD, 0, 1, 0,
        out, NN * DD, NN, DD, DD, 1, DD, 4, b5, a5, nullptr, 0, x, NN * DD);
}